// Round 1
// baseline (1153.767 us; speedup 1.0000x reference)
//
#include <hip/hip_runtime.h>
#include <hip/hip_bf16.h>

// Problem constants (fixed by the reference)
#define NN 50000
#define EE 800000
#define FF 128
#define HH 256
#define GG 512
#define TT 5

// ---------------------------------------------------------------------------
// Preprocessing kernels
// ---------------------------------------------------------------------------

__global__ void count_kernel(const int* __restrict__ dst, int* __restrict__ cnt, int e) {
    int t = blockIdx.x * blockDim.x + threadIdx.x;
    if (t < e) atomicAdd(&cnt[dst[t]], 1);
}

__global__ void dinv_kernel(const int* __restrict__ cnt, float* __restrict__ dinv,
                            float* __restrict__ selfnorm, int n) {
    int i = blockIdx.x * blockDim.x + threadIdx.x;
    if (i >= n) return;
    float deg = (float)(cnt[i] + 1);   // +1 self loop; exact integer
    float dv  = 1.0f / sqrtf(deg);     // match numpy 1/sqrt fp32 semantics
    dinv[i] = dv;
    selfnorm[i] = dv * dv;
}

// Single-block exclusive scan of cnt -> row_ptr, also zeroes cursor.
__global__ void scan_kernel(const int* __restrict__ cnt, int* __restrict__ row_ptr,
                            int* __restrict__ cursor, int n) {
    __shared__ int smem[1024];
    __shared__ int carry;
    if (threadIdx.x == 0) carry = 0;
    __syncthreads();
    for (int base = 0; base < n; base += 1024) {
        int i = base + (int)threadIdx.x;
        int v = (i < n) ? cnt[i] : 0;
        smem[threadIdx.x] = v;
        __syncthreads();
        for (int off = 1; off < 1024; off <<= 1) {
            int t = (threadIdx.x >= (unsigned)off) ? smem[threadIdx.x - off] : 0;
            __syncthreads();
            smem[threadIdx.x] += t;
            __syncthreads();
        }
        int incl = smem[threadIdx.x];
        if (i < n) {
            row_ptr[i] = carry + incl - v;  // exclusive
            cursor[i] = 0;
        }
        __syncthreads();
        if (threadIdx.x == 1023) carry += smem[1023];
        __syncthreads();
    }
    if (threadIdx.x == 0) row_ptr[n] = carry;
}

__global__ void scatter_kernel(const int* __restrict__ src, const int* __restrict__ dst,
                               const int* __restrict__ row_ptr, int* __restrict__ cursor,
                               int* __restrict__ col, float* __restrict__ enorm,
                               const float* __restrict__ dinv, int e) {
    int t = blockIdx.x * blockDim.x + threadIdx.x;
    if (t >= e) return;
    int s = src[t], d = dst[t];
    int pos = row_ptr[d] + atomicAdd(&cursor[d], 1);
    col[pos] = s;
    enorm[pos] = dinv[s] * dinv[d];
}

// batch is sorted; bp[g] = lower_bound(batch, g); bp[G] = N
__global__ void bp_kernel(const int* __restrict__ batch, int* __restrict__ bp, int n, int g) {
    int t = blockIdx.x * blockDim.x + threadIdx.x;
    if (t > g) return;
    int lo = 0, hi = n;
    while (lo < hi) {
        int mid = (lo + hi) >> 1;
        if (batch[mid] < t) lo = mid + 1; else hi = mid;
    }
    bp[t] = lo;
}

// ---------------------------------------------------------------------------
// GEMM: C[M x 256] = A[M x K] @ B[K x 256], fp32, row-major
// block = 256 threads, tile 64x64, thread tile 4x4, BK=16
// ---------------------------------------------------------------------------
__global__ __launch_bounds__(256) void gemm_kernel(const float* __restrict__ A,
                                                   const float* __restrict__ B,
                                                   float* __restrict__ C,
                                                   int M, int K) {
    __shared__ float As[16][68];  // +4 pad: write banks (ak*4+r)%32 -> conflict-free-ish
    __shared__ float Bs[16][64];
    int bm = blockIdx.x * 64;
    int bn = blockIdx.y * 64;
    int tid = threadIdx.x;
    int tx = tid & 15;
    int ty = tid >> 4;

    float acc[4][4] = {};

    int ar = tid >> 4;   // 0..15
    int ak = tid & 15;   // 0..15
    int br = tid >> 6;   // 0..3
    int bc = tid & 63;   // 0..63

    for (int k0 = 0; k0 < K; k0 += 16) {
        #pragma unroll
        for (int r = ar; r < 64; r += 16) {
            int grow = bm + r;
            As[ak][r] = (grow < M) ? A[(size_t)grow * K + k0 + ak] : 0.0f;
        }
        #pragma unroll
        for (int r = br; r < 16; r += 4) {
            Bs[r][bc] = B[(size_t)(k0 + r) * 256 + bn + bc];
        }
        __syncthreads();
        #pragma unroll
        for (int kk = 0; kk < 16; kk++) {
            float a[4], b[4];
            #pragma unroll
            for (int u = 0; u < 4; u++) a[u] = As[kk][ty * 4 + u];
            #pragma unroll
            for (int v = 0; v < 4; v++) b[v] = Bs[kk][tx * 4 + v];
            #pragma unroll
            for (int u = 0; u < 4; u++)
                #pragma unroll
                for (int v = 0; v < 4; v++)
                    acc[u][v] += a[u] * b[v];
        }
        __syncthreads();
    }
    #pragma unroll
    for (int u = 0; u < 4; u++) {
        int grow = bm + ty * 4 + u;
        if (grow < M) {
            #pragma unroll
            for (int v = 0; v < 4; v++)
                C[(size_t)grow * 256 + bn + tx * 4 + v] = acc[u][v];
        }
    }
}

// ---------------------------------------------------------------------------
// Aggregation: out[i][c] = relu( selfnorm[i]*HW[i][c]
//                              + sum_e enorm[e]*HW[col[e]][c] + bias[c] )
// block = 256 threads (one per channel), grid = N
// ---------------------------------------------------------------------------
__global__ __launch_bounds__(256) void agg_kernel(const float* __restrict__ HW,
                                                  const int* __restrict__ row_ptr,
                                                  const int* __restrict__ col,
                                                  const float* __restrict__ enorm,
                                                  const float* __restrict__ selfnorm,
                                                  const float* __restrict__ bias,
                                                  float* __restrict__ out) {
    int i = blockIdx.x;
    int c = threadIdx.x;
    __shared__ int   s_col[64];
    __shared__ float s_nrm[64];
    int beg = row_ptr[i], end = row_ptr[i + 1];
    float acc = selfnorm[i] * HW[(size_t)i * 256 + c];
    for (int base = beg; base < end; base += 64) {
        int m = end - base;
        if (m > 64) m = 64;
        if (c < m) { s_col[c] = col[base + c]; s_nrm[c] = enorm[base + c]; }
        __syncthreads();
        for (int j = 0; j < m; j++)
            acc += s_nrm[j] * HW[(size_t)s_col[j] * 256 + c];
        __syncthreads();
    }
    out[(size_t)i * 256 + c] = fmaxf(acc + bias[c], 0.0f);
}

// ---------------------------------------------------------------------------
// Pool: pooled[g][c] = mean over nodes in [bp[g], bp[g+1]) of h[i][c]
// ---------------------------------------------------------------------------
__global__ __launch_bounds__(256) void pool_kernel(const float* __restrict__ h,
                                                   const int* __restrict__ bp,
                                                   float* __restrict__ pooled) {
    int g = blockIdx.x;
    int c = threadIdx.x;
    int beg = bp[g], end = bp[g + 1];
    float acc = 0.0f;
    for (int i = beg; i < end; i++) acc += h[(size_t)i * 256 + c];
    float cnt = (float)(end - beg);
    pooled[(size_t)g * 256 + c] = acc / fmaxf(cnt, 1.0f);
}

// out[g][t] = sum_c pooled[g][c] * Wout[c][t] + bout[t]
__global__ __launch_bounds__(64) void head_kernel(const float* __restrict__ pooled,
                                                  const float* __restrict__ Wout,
                                                  const float* __restrict__ bout,
                                                  float* __restrict__ out) {
    int g = blockIdx.x;
    int t = threadIdx.x;
    if (t >= TT) return;
    float s = 0.0f;
    for (int c = 0; c < HH; c++)
        s += pooled[(size_t)g * HH + c] * Wout[c * TT + t];
    out[(size_t)g * TT + t] = s + bout[t];
}

// ---------------------------------------------------------------------------
// Launch
// ---------------------------------------------------------------------------
extern "C" void kernel_launch(void* const* d_in, const int* in_sizes, int n_in,
                              void* d_out, int out_size, void* d_ws, size_t ws_size,
                              hipStream_t stream) {
    const float* x     = (const float*)d_in[0];
    const int*   esrc  = (const int*)d_in[1];        // edge_index row 0
    const int*   edst  = ((const int*)d_in[1]) + EE; // edge_index row 1
    const int*   batch = (const int*)d_in[2];
    const float* W0 = (const float*)d_in[3];  const float* b0 = (const float*)d_in[4];
    const float* W1 = (const float*)d_in[5];  const float* b1 = (const float*)d_in[6];
    const float* W2 = (const float*)d_in[7];  const float* b2 = (const float*)d_in[8];
    const float* W3 = (const float*)d_in[9];  const float* b3 = (const float*)d_in[10];
    const float* Wout = (const float*)d_in[11]; const float* bout = (const float*)d_in[12];
    float* out = (float*)d_out;

    // Workspace carve-up (aligned to 256B)
    char* p = (char*)d_ws;
    size_t off = 0;
    auto alloc = [&](size_t bytes) {
        void* r = p + off;
        off += (bytes + 255) & ~(size_t)255;
        return r;
    };
    int*   cnt      = (int*)alloc((size_t)NN * 4);
    int*   row_ptr  = (int*)alloc((size_t)(NN + 1) * 4);
    int*   cursor   = (int*)alloc((size_t)NN * 4);
    float* dinv     = (float*)alloc((size_t)NN * 4);
    float* selfnorm = (float*)alloc((size_t)NN * 4);
    int*   bp       = (int*)alloc((size_t)(GG + 1) * 4);
    int*   col      = (int*)alloc((size_t)EE * 4);
    float* enorm    = (float*)alloc((size_t)EE * 4);
    float* bufA     = (float*)alloc((size_t)NN * HH * 4); // HW
    float* bufB     = (float*)alloc((size_t)NN * HH * 4); // h
    float* pooled   = (float*)alloc((size_t)GG * HH * 4);
    (void)ws_size;

    // --- preprocessing ---
    hipMemsetAsync(cnt, 0, (size_t)NN * 4, stream);
    count_kernel<<<(EE + 255) / 256, 256, 0, stream>>>(edst, cnt, EE);
    dinv_kernel<<<(NN + 255) / 256, 256, 0, stream>>>(cnt, dinv, selfnorm, NN);
    scan_kernel<<<1, 1024, 0, stream>>>(cnt, row_ptr, cursor, NN);
    scatter_kernel<<<(EE + 255) / 256, 256, 0, stream>>>(esrc, edst, row_ptr, cursor,
                                                         col, enorm, dinv, EE);
    bp_kernel<<<(GG + 64) / 64, 64, 0, stream>>>(batch, bp, NN, GG);

    dim3 ggrid((NN + 63) / 64, HH / 64);

    // --- layer 0: x (N x 128) ---
    gemm_kernel<<<ggrid, 256, 0, stream>>>(x, W0, bufA, NN, FF);
    agg_kernel<<<NN, 256, 0, stream>>>(bufA, row_ptr, col, enorm, selfnorm, b0, bufB);
    // --- layer 1 ---
    gemm_kernel<<<ggrid, 256, 0, stream>>>(bufB, W1, bufA, NN, HH);
    agg_kernel<<<NN, 256, 0, stream>>>(bufA, row_ptr, col, enorm, selfnorm, b1, bufB);
    // --- layer 2 ---
    gemm_kernel<<<ggrid, 256, 0, stream>>>(bufB, W2, bufA, NN, HH);
    agg_kernel<<<NN, 256, 0, stream>>>(bufA, row_ptr, col, enorm, selfnorm, b2, bufB);
    // --- layer 3 ---
    gemm_kernel<<<ggrid, 256, 0, stream>>>(bufB, W3, bufA, NN, HH);
    agg_kernel<<<NN, 256, 0, stream>>>(bufA, row_ptr, col, enorm, selfnorm, b3, bufB);

    // --- pool + head ---
    pool_kernel<<<GG, 256, 0, stream>>>(bufB, bp, pooled);
    head_kernel<<<GG, 64, 0, stream>>>(pooled, Wout, bout, out);
}

// Round 2
// 633.048 us; speedup vs baseline: 1.8226x; 1.8226x over previous
//
#include <hip/hip_runtime.h>
#include <hip/hip_bf16.h>

#define NN 50000
#define EE 800000
#define FF 128
#define HH 256
#define GG 512
#define TT 5

typedef __attribute__((ext_vector_type(8))) short bf16x8_t;
typedef __attribute__((ext_vector_type(4))) float f32x4_t;

__device__ __forceinline__ ushort f2b(float f) {
    union { float f; uint u; } c; c.f = f;
    uint u = c.u;
    u += 0x7fffu + ((u >> 16) & 1u);
    return (ushort)(u >> 16);
}
__device__ __forceinline__ float b2f(ushort h) {
    union { uint u; float f; } c; c.u = ((uint)h) << 16;
    return c.f;
}
__device__ __forceinline__ void b2x2(uint q, float& a, float& b) {
    union { uint u; float f; } lo, hi;
    lo.u = q << 16; hi.u = q & 0xffff0000u;
    a = lo.f; b = hi.f;
}

// ---------------------------------------------------------------------------
// Preprocessing
// ---------------------------------------------------------------------------
__global__ void count_kernel(const int* __restrict__ dst, int* __restrict__ cnt, int e) {
    int t = blockIdx.x * blockDim.x + threadIdx.x;
    if (t < e) atomicAdd(&cnt[dst[t]], 1);
}

__global__ void dinv_kernel(const int* __restrict__ cnt, float* __restrict__ dinv,
                            float* __restrict__ selfnorm, int n) {
    int i = blockIdx.x * blockDim.x + threadIdx.x;
    if (i >= n) return;
    float deg = (float)(cnt[i] + 1);
    float dv  = 1.0f / sqrtf(deg);
    dinv[i] = dv;
    selfnorm[i] = dv * dv;
}

__global__ __launch_bounds__(256) void blocksum_kernel(const int* __restrict__ cnt,
                                                       int* __restrict__ bsum, int n) {
    __shared__ int sm[256];
    int i = blockIdx.x * 256 + threadIdx.x;
    sm[threadIdx.x] = (i < n) ? cnt[i] : 0;
    __syncthreads();
    for (int s = 128; s > 0; s >>= 1) {
        if ((int)threadIdx.x < s) sm[threadIdx.x] += sm[threadIdx.x + s];
        __syncthreads();
    }
    if (threadIdx.x == 0) bsum[blockIdx.x] = sm[0];
}

// 1 block, inclusive scan of nb (<=256) block sums -> exclusive offsets
__global__ __launch_bounds__(256) void scanb_kernel(const int* __restrict__ bsum,
                                                    int* __restrict__ boff, int nb) {
    __shared__ int sm[256];
    int v = ((int)threadIdx.x < nb) ? bsum[threadIdx.x] : 0;
    sm[threadIdx.x] = v;
    __syncthreads();
    for (int off = 1; off < 256; off <<= 1) {
        int t = (threadIdx.x >= (unsigned)off) ? sm[threadIdx.x - off] : 0;
        __syncthreads();
        sm[threadIdx.x] += t;
        __syncthreads();
    }
    if ((int)threadIdx.x < nb) boff[threadIdx.x] = sm[threadIdx.x] - v;
}

__global__ __launch_bounds__(256) void rowptr_kernel(const int* __restrict__ cnt,
                                                     const int* __restrict__ boff,
                                                     int* __restrict__ row_ptr,
                                                     int* __restrict__ cursor, int n) {
    __shared__ int sm[256];
    int i = blockIdx.x * 256 + threadIdx.x;
    int v = (i < n) ? cnt[i] : 0;
    sm[threadIdx.x] = v;
    __syncthreads();
    for (int off = 1; off < 256; off <<= 1) {
        int t = (threadIdx.x >= (unsigned)off) ? sm[threadIdx.x - off] : 0;
        __syncthreads();
        sm[threadIdx.x] += t;
        __syncthreads();
    }
    int excl = boff[blockIdx.x] + sm[threadIdx.x] - v;
    if (i < n) { row_ptr[i] = excl; cursor[i] = 0; }
    if (i == n - 1) row_ptr[n] = excl + v;
}

__global__ void scatter_kernel(const int* __restrict__ src, const int* __restrict__ dst,
                               const int* __restrict__ row_ptr, int* __restrict__ cursor,
                               int* __restrict__ col, float* __restrict__ enorm,
                               const float* __restrict__ dinv, int e) {
    int t = blockIdx.x * blockDim.x + threadIdx.x;
    if (t >= e) return;
    int s = src[t], d = dst[t];
    int pos = row_ptr[d] + atomicAdd(&cursor[d], 1);
    col[pos] = s;
    enorm[pos] = dinv[s] * dinv[d];
}

__global__ void bp_kernel(const int* __restrict__ batch, int* __restrict__ bp, int n, int g) {
    int t = blockIdx.x * blockDim.x + threadIdx.x;
    if (t > g) return;
    int lo = 0, hi = n;
    while (lo < hi) {
        int mid = (lo + hi) >> 1;
        if (batch[mid] < t) lo = mid + 1; else hi = mid;
    }
    bp[t] = lo;
}

// x fp32 -> bf16, vectorized
__global__ void cvtx_kernel(const float* __restrict__ x, ushort* __restrict__ xb, int n4) {
    int i = blockIdx.x * 256 + threadIdx.x;
    if (i >= n4) return;
    float4 v = ((const float4*)x)[i];
    ushort4 o;
    o.x = f2b(v.x); o.y = f2b(v.y); o.z = f2b(v.z); o.w = f2b(v.w);
    ((ushort4*)xb)[i] = o;
}

// W [K][256] fp32 -> Wt [256][K] bf16
__global__ void wt_kernel(const float* __restrict__ W, ushort* __restrict__ Wt, int K) {
    int idx = blockIdx.x * 256 + threadIdx.x;
    if (idx >= K * 256) return;
    int k = idx >> 8, n = idx & 255;
    Wt[(size_t)n * K + k] = f2b(W[idx]);
}

// ---------------------------------------------------------------------------
// Aggregation (pure): out[i] = selfnorm[i]*H[i] + sum_e enorm[e]*H[col[e]]
// one wave per node, bf16 in/out, fp32 accumulate. C = 128 or 256.
// ---------------------------------------------------------------------------
template<int C>
__global__ __launch_bounds__(256) void agg_kernel(const ushort* __restrict__ H,
                                                  const int* __restrict__ row_ptr,
                                                  const int* __restrict__ col,
                                                  const float* __restrict__ enorm,
                                                  const float* __restrict__ selfnorm,
                                                  ushort* __restrict__ out) {
    constexpr int CPL = C / 64;  // bf16 per lane: 2 or 4
    int wave = threadIdx.x >> 6;
    int lane = threadIdx.x & 63;
    int i = blockIdx.x * 4 + wave;
    if (i >= NN) return;

    float acc[CPL];
    float sn = selfnorm[i];
    {
        const ushort* p = H + (size_t)i * C + lane * CPL;
        if (CPL == 2) {
            uint q = *(const uint*)p;
            float a, b; b2x2(q, a, b);
            acc[0] = sn * a; acc[1] = sn * b;
        } else {
            uint2 q = *(const uint2*)p;
            float a, b, c, d; b2x2(q.x, a, b); b2x2(q.y, c, d);
            acc[0] = sn * a; acc[1] = sn * b; acc[2] = sn * c; acc[3] = sn * d;
        }
    }
    int beg = row_ptr[i], end = row_ptr[i + 1];
    for (int base = beg; base < end; base += 64) {
        int t = base + lane;
        int idxv = (t < end) ? col[t] : 0;
        float ev = (t < end) ? enorm[t] : 0.0f;
        int m = end - base; if (m > 64) m = 64;
        for (int j = 0; j < m; j++) {
            int   s = __shfl(idxv, j);
            float w = __shfl(ev, j);
            const ushort* p = H + (size_t)s * C + lane * CPL;
            if (CPL == 2) {
                uint q = *(const uint*)p;
                float a, b; b2x2(q, a, b);
                acc[0] += w * a; acc[1] += w * b;
            } else {
                uint2 q = *(const uint2*)p;
                float a, b, c, d; b2x2(q.x, a, b); b2x2(q.y, c, d);
                acc[0] += w * a; acc[1] += w * b; acc[2] += w * c; acc[3] += w * d;
            }
        }
    }
    ushort* po = out + (size_t)i * C + lane * CPL;
    if (CPL == 2) {
        uint o = (uint)f2b(acc[0]) | ((uint)f2b(acc[1]) << 16);
        *(uint*)po = o;
    } else {
        uint2 o;
        o.x = (uint)f2b(acc[0]) | ((uint)f2b(acc[1]) << 16);
        o.y = (uint)f2b(acc[2]) | ((uint)f2b(acc[3]) << 16);
        *(uint2*)po = o;
    }
}

// ---------------------------------------------------------------------------
// MFMA GEMM: C[M x 256] = relu(A[M x K](bf16) @ W(bf16, pre-transposed [256][K]) + bias)
// block = 256 (4 waves), BM=128 (32 rows/wave), BN=64, no LDS (B slice L2-resident)
// ---------------------------------------------------------------------------
template<int K>
__global__ __launch_bounds__(256) void gemm_kernel(const ushort* __restrict__ A,
                                                   const ushort* __restrict__ Bt,
                                                   const float* __restrict__ bias,
                                                   ushort* __restrict__ C, int M) {
    int wave = threadIdx.x >> 6;
    int lane = threadIdx.x & 63;
    int quad = lane >> 4;
    int r = lane & 15;
    int bm = blockIdx.x * 128 + wave * 32;
    int bn = blockIdx.y * 64;

    int rowA0 = bm + r;       if (rowA0 >= M) rowA0 = M - 1;
    int rowA1 = bm + 16 + r;  if (rowA1 >= M) rowA1 = M - 1;
    const ushort* pA0 = A + (size_t)rowA0 * K + quad * 8;
    const ushort* pA1 = A + (size_t)rowA1 * K + quad * 8;
    const ushort* pB0 = Bt + (size_t)(bn + r) * K + quad * 8;

    f32x4_t acc[2][4];
    #pragma unroll
    for (int mt = 0; mt < 2; mt++)
        #pragma unroll
        for (int nt = 0; nt < 4; nt++)
            acc[mt][nt] = (f32x4_t){0.f, 0.f, 0.f, 0.f};

    #pragma unroll 2
    for (int kt = 0; kt < K; kt += 32) {
        bf16x8_t a0 = *(const bf16x8_t*)(pA0 + kt);
        bf16x8_t a1 = *(const bf16x8_t*)(pA1 + kt);
        bf16x8_t b[4];
        #pragma unroll
        for (int nt = 0; nt < 4; nt++)
            b[nt] = *(const bf16x8_t*)(pB0 + (size_t)nt * 16 * K + kt);
        #pragma unroll
        for (int nt = 0; nt < 4; nt++) {
            acc[0][nt] = __builtin_amdgcn_mfma_f32_16x16x32_bf16(a0, b[nt], acc[0][nt], 0, 0, 0);
            acc[1][nt] = __builtin_amdgcn_mfma_f32_16x16x32_bf16(a1, b[nt], acc[1][nt], 0, 0, 0);
        }
    }

    #pragma unroll
    for (int mt = 0; mt < 2; mt++) {
        #pragma unroll
        for (int i = 0; i < 4; i++) {
            int grow = bm + mt * 16 + quad * 4 + i;
            if (grow < M) {
                #pragma unroll
                for (int nt = 0; nt < 4; nt++) {
                    int gcol = bn + nt * 16 + r;
                    float v = acc[mt][nt][i] + bias[gcol];
                    v = fmaxf(v, 0.0f);
                    C[(size_t)grow * 256 + gcol] = f2b(v);
                }
            }
        }
    }
}

// ---------------------------------------------------------------------------
// Pool (partial, 8-way row split, fp32 atomics) + head
// ---------------------------------------------------------------------------
__global__ __launch_bounds__(256) void pool_kernel(const ushort* __restrict__ H,
                                                   const int* __restrict__ bp,
                                                   float* __restrict__ pooled) {
    int g = blockIdx.x, part = blockIdx.y;
    int beg = bp[g], end = bp[g + 1];
    int cnt = end - beg;
    int per = (cnt + 7) >> 3;
    int rb = beg + part * per;
    int re = rb + per; if (re > end) re = end;
    if (rb >= re) return;
    int c = threadIdx.x;
    float acc = 0.0f;
    for (int i = rb; i < re; i++) acc += b2f(H[(size_t)i * 256 + c]);
    atomicAdd(&pooled[(size_t)g * 256 + c], acc);
}

__global__ __launch_bounds__(64) void head_kernel(const float* __restrict__ pooled,
                                                  const int* __restrict__ bp,
                                                  const float* __restrict__ Wout,
                                                  const float* __restrict__ bout,
                                                  float* __restrict__ out) {
    int g = blockIdx.x;
    int lane = threadIdx.x;
    float inv = 1.0f / fmaxf((float)(bp[g + 1] - bp[g]), 1.0f);
    const float* pg = pooled + (size_t)g * HH;
    float s[TT] = {};
    for (int c = lane; c < HH; c += 64) {
        float p = pg[c] * inv;
        #pragma unroll
        for (int t = 0; t < TT; t++) s[t] += p * Wout[c * TT + t];
    }
    #pragma unroll
    for (int t = 0; t < TT; t++) {
        float v = s[t];
        for (int off = 32; off > 0; off >>= 1) v += __shfl_down(v, off);
        if (lane == 0) out[(size_t)g * TT + t] = v + bout[t];
    }
}

// ---------------------------------------------------------------------------
// Launch
// ---------------------------------------------------------------------------
extern "C" void kernel_launch(void* const* d_in, const int* in_sizes, int n_in,
                              void* d_out, int out_size, void* d_ws, size_t ws_size,
                              hipStream_t stream) {
    const float* x     = (const float*)d_in[0];
    const int*   esrc  = (const int*)d_in[1];
    const int*   edst  = ((const int*)d_in[1]) + EE;
    const int*   batch = (const int*)d_in[2];
    const float* W0 = (const float*)d_in[3];  const float* b0 = (const float*)d_in[4];
    const float* W1 = (const float*)d_in[5];  const float* b1 = (const float*)d_in[6];
    const float* W2 = (const float*)d_in[7];  const float* b2 = (const float*)d_in[8];
    const float* W3 = (const float*)d_in[9];  const float* b3 = (const float*)d_in[10];
    const float* Wout = (const float*)d_in[11]; const float* bout = (const float*)d_in[12];
    float* out = (float*)d_out;

    char* p = (char*)d_ws;
    size_t off = 0;
    auto alloc = [&](size_t bytes) {
        void* r = p + off;
        off += (bytes + 255) & ~(size_t)255;
        return r;
    };
    int*    cnt      = (int*)alloc((size_t)NN * 4);
    int*    row_ptr  = (int*)alloc((size_t)(NN + 1) * 4);
    int*    cursor   = (int*)alloc((size_t)NN * 4);
    float*  dinv     = (float*)alloc((size_t)NN * 4);
    float*  selfnorm = (float*)alloc((size_t)NN * 4);
    int*    bsum     = (int*)alloc(256 * 4);
    int*    boff     = (int*)alloc(256 * 4);
    int*    bp       = (int*)alloc((size_t)(GG + 1) * 4);
    int*    col      = (int*)alloc((size_t)EE * 4);
    float*  enorm    = (float*)alloc((size_t)EE * 4);
    ushort* xb       = (ushort*)alloc((size_t)NN * FF * 2);
    ushort* aggX     = (ushort*)alloc((size_t)NN * FF * 2);
    ushort* hA       = (ushort*)alloc((size_t)NN * HH * 2);
    ushort* hB       = (ushort*)alloc((size_t)NN * HH * 2);
    ushort* Wt0      = (ushort*)alloc((size_t)FF * HH * 2);
    ushort* Wt1      = (ushort*)alloc((size_t)HH * HH * 2);
    ushort* Wt2      = (ushort*)alloc((size_t)HH * HH * 2);
    ushort* Wt3      = (ushort*)alloc((size_t)HH * HH * 2);
    float*  pooled   = (float*)alloc((size_t)GG * HH * 4);
    (void)ws_size;

    const int NB = (NN + 255) / 256;  // 196

    // --- preprocessing ---
    hipMemsetAsync(cnt, 0, (size_t)NN * 4, stream);
    hipMemsetAsync(pooled, 0, (size_t)GG * HH * 4, stream);
    count_kernel<<<(EE + 255) / 256, 256, 0, stream>>>(edst, cnt, EE);
    dinv_kernel<<<(NN + 255) / 256, 256, 0, stream>>>(cnt, dinv, selfnorm, NN);
    blocksum_kernel<<<NB, 256, 0, stream>>>(cnt, bsum, NN);
    scanb_kernel<<<1, 256, 0, stream>>>(bsum, boff, NB);
    rowptr_kernel<<<NB, 256, 0, stream>>>(cnt, boff, row_ptr, cursor, NN);
    scatter_kernel<<<(EE + 255) / 256, 256, 0, stream>>>(esrc, edst, row_ptr, cursor,
                                                         col, enorm, dinv, EE);
    bp_kernel<<<(GG + 64) / 64, 64, 0, stream>>>(batch, bp, NN, GG);

    // --- casts ---
    cvtx_kernel<<<(NN * FF / 4 + 255) / 256, 256, 0, stream>>>(x, xb, NN * FF / 4);
    wt_kernel<<<FF, 256, 0, stream>>>(W0, Wt0, FF);
    wt_kernel<<<HH, 256, 0, stream>>>(W1, Wt1, HH);
    wt_kernel<<<HH, 256, 0, stream>>>(W2, Wt2, HH);
    wt_kernel<<<HH, 256, 0, stream>>>(W3, Wt3, HH);

    dim3 ggrid((NN + 127) / 128, 4);
    int aggblocks = (NN + 3) / 4;

    // --- layer 0: agg on x (128 cols) then GEMM K=128 ---
    agg_kernel<FF><<<aggblocks, 256, 0, stream>>>(xb, row_ptr, col, enorm, selfnorm, aggX);
    gemm_kernel<FF><<<ggrid, 256, 0, stream>>>(aggX, Wt0, b0, hA, NN);
    // --- layer 1 ---
    agg_kernel<HH><<<aggblocks, 256, 0, stream>>>(hA, row_ptr, col, enorm, selfnorm, hB);
    gemm_kernel<HH><<<ggrid, 256, 0, stream>>>(hB, Wt1, b1, hA, NN);
    // --- layer 2 ---
    agg_kernel<HH><<<aggblocks, 256, 0, stream>>>(hA, row_ptr, col, enorm, selfnorm, hB);
    gemm_kernel<HH><<<ggrid, 256, 0, stream>>>(hB, Wt2, b2, hA, NN);
    // --- layer 3 ---
    agg_kernel<HH><<<aggblocks, 256, 0, stream>>>(hA, row_ptr, col, enorm, selfnorm, hB);
    gemm_kernel<HH><<<ggrid, 256, 0, stream>>>(hB, Wt3, b3, hA, NN);

    // --- pool + head ---
    dim3 pgrid(GG, 8);
    pool_kernel<<<pgrid, 256, 0, stream>>>(hA, bp, pooled);
    head_kernel<<<GG, 64, 0, stream>>>(pooled, bp, Wout, bout, out);
}

// Round 3
// 586.512 us; speedup vs baseline: 1.9672x; 1.0793x over previous
//
#include <hip/hip_runtime.h>
#include <hip/hip_bf16.h>

#define NN 50000
#define EE 800000
#define FF 128
#define HH 256
#define GG 512
#define TT 5

typedef __attribute__((ext_vector_type(8))) short bf16x8_t;
typedef __attribute__((ext_vector_type(4))) float f32x4_t;

__device__ __forceinline__ ushort f2b(float f) {
    union { float f; uint u; } c; c.f = f;
    uint u = c.u;
    u += 0x7fffu + ((u >> 16) & 1u);
    return (ushort)(u >> 16);
}
__device__ __forceinline__ float b2f(ushort h) {
    union { uint u; float f; } c; c.u = ((uint)h) << 16;
    return c.f;
}
__device__ __forceinline__ void b2x2(uint q, float& a, float& b) {
    union { uint u; float f; } lo, hi;
    lo.u = q << 16; hi.u = q & 0xffff0000u;
    a = lo.f; b = hi.f;
}
__device__ __forceinline__ uint pack2(float a, float b) {
    return (uint)f2b(a) | ((uint)f2b(b) << 16);
}

// ---------------------------------------------------------------------------
// Preprocessing
// ---------------------------------------------------------------------------
__global__ void count_kernel(const int* __restrict__ dst, int* __restrict__ cnt, int e) {
    int t = blockIdx.x * blockDim.x + threadIdx.x;
    if (t < e) atomicAdd(&cnt[dst[t]], 1);
}

__global__ __launch_bounds__(256) void blocksum_kernel(const int* __restrict__ cnt,
                                                       int* __restrict__ bsum, int n) {
    __shared__ int sm[256];
    int i = blockIdx.x * 256 + threadIdx.x;
    sm[threadIdx.x] = (i < n) ? cnt[i] : 0;
    __syncthreads();
    for (int s = 128; s > 0; s >>= 1) {
        if ((int)threadIdx.x < s) sm[threadIdx.x] += sm[threadIdx.x + s];
        __syncthreads();
    }
    if (threadIdx.x == 0) bsum[blockIdx.x] = sm[0];
}

__global__ __launch_bounds__(256) void scanb_kernel(const int* __restrict__ bsum,
                                                    int* __restrict__ boff, int nb) {
    __shared__ int sm[256];
    int v = ((int)threadIdx.x < nb) ? bsum[threadIdx.x] : 0;
    sm[threadIdx.x] = v;
    __syncthreads();
    for (int off = 1; off < 256; off <<= 1) {
        int t = (threadIdx.x >= (unsigned)off) ? sm[threadIdx.x - off] : 0;
        __syncthreads();
        sm[threadIdx.x] += t;
        __syncthreads();
    }
    if ((int)threadIdx.x < nb) boff[threadIdx.x] = sm[threadIdx.x] - v;
}

// per-block scan + fused dinv/selfnorm/cursor init
__global__ __launch_bounds__(256) void rowptr_kernel(const int* __restrict__ cnt,
                                                     const int* __restrict__ boff,
                                                     int* __restrict__ row_ptr,
                                                     int* __restrict__ cursor,
                                                     float* __restrict__ dinv,
                                                     float* __restrict__ selfnorm, int n) {
    __shared__ int sm[256];
    int i = blockIdx.x * 256 + threadIdx.x;
    int v = (i < n) ? cnt[i] : 0;
    sm[threadIdx.x] = v;
    __syncthreads();
    for (int off = 1; off < 256; off <<= 1) {
        int t = (threadIdx.x >= (unsigned)off) ? sm[threadIdx.x - off] : 0;
        __syncthreads();
        sm[threadIdx.x] += t;
        __syncthreads();
    }
    int excl = boff[blockIdx.x] + sm[threadIdx.x] - v;
    if (i < n) {
        row_ptr[i] = excl;
        cursor[i] = 0;
        float dv = 1.0f / sqrtf((float)(v + 1));
        dinv[i] = dv;
        selfnorm[i] = dv * dv;
    }
    if (i == n - 1) row_ptr[n] = excl + v;
}

__global__ void scatter_kernel(const int* __restrict__ src, const int* __restrict__ dst,
                               const int* __restrict__ row_ptr, int* __restrict__ cursor,
                               uint2* __restrict__ meta,
                               const float* __restrict__ dinv, int e) {
    int t = blockIdx.x * blockDim.x + threadIdx.x;
    if (t >= e) return;
    int s = src[t], d = dst[t];
    int pos = row_ptr[d] + atomicAdd(&cursor[d], 1);
    uint2 m;
    m.x = (uint)s;
    m.y = __float_as_uint(dinv[s] * dinv[d]);
    meta[pos] = m;
}

__global__ void bp_kernel(const int* __restrict__ batch, int* __restrict__ bp, int n, int g) {
    int t = blockIdx.x * blockDim.x + threadIdx.x;
    if (t > g) return;
    int lo = 0, hi = n;
    while (lo < hi) {
        int mid = (lo + hi) >> 1;
        if (batch[mid] < t) lo = mid + 1; else hi = mid;
    }
    bp[t] = lo;
}

__global__ void cvtx_kernel(const float* __restrict__ x, ushort* __restrict__ xb, int n4) {
    int i = blockIdx.x * 256 + threadIdx.x;
    if (i >= n4) return;
    float4 v = ((const float4*)x)[i];
    ushort4 o;
    o.x = f2b(v.x); o.y = f2b(v.y); o.z = f2b(v.z); o.w = f2b(v.w);
    ((ushort4*)xb)[i] = o;
}

// All four W [K][256] fp32 -> Wt [256][K] bf16 in one launch
__global__ __launch_bounds__(256) void wt_all_kernel(const float* __restrict__ W0,
                                                     const float* __restrict__ W1,
                                                     const float* __restrict__ W2,
                                                     const float* __restrict__ W3,
                                                     ushort* __restrict__ Wt0,
                                                     ushort* __restrict__ Wt1,
                                                     ushort* __restrict__ Wt2,
                                                     ushort* __restrict__ Wt3) {
    int b = blockIdx.x;
    const float* W; ushort* Wt; int K, kb;
    if (b < FF)            { W = W0; Wt = Wt0; K = FF; kb = b; }
    else if (b < FF + HH)  { W = W1; Wt = Wt1; K = HH; kb = b - FF; }
    else if (b < FF + 2*HH){ W = W2; Wt = Wt2; K = HH; kb = b - FF - HH; }
    else                   { W = W3; Wt = Wt3; K = HH; kb = b - FF - 2*HH; }
    int n = threadIdx.x;
    Wt[(size_t)n * K + kb] = f2b(W[(size_t)kb * 256 + n]);
}

// ---------------------------------------------------------------------------
// Aggregation v2: wave per node, two 32-lane halves process even/odd edges
// with uint4 (C=256) / uint2 (C=128) gathers; cross-half shfl_xor reduce.
// ---------------------------------------------------------------------------
template<int C>
__global__ __launch_bounds__(256) void agg_kernel(const ushort* __restrict__ H,
                                                  const int* __restrict__ row_ptr,
                                                  const uint2* __restrict__ meta,
                                                  const float* __restrict__ selfnorm,
                                                  ushort* __restrict__ out) {
    constexpr int UPL = C / 64;   // uints per lane: 4 (C=256) or 2 (C=128)
    int wave = threadIdx.x >> 6;
    int lane = threadIdx.x & 63;
    int h = lane >> 5;
    int cl = lane & 31;
    int i = blockIdx.x * 4 + wave;
    if (i >= NN) return;

    float acc[2 * UPL];
    #pragma unroll
    for (int k = 0; k < 2 * UPL; k++) acc[k] = 0.0f;

    const uint* rowbase = (const uint*)H;
    if (h == 0) {
        float sn = selfnorm[i];
        const uint* p = rowbase + (size_t)i * (C / 2) + cl * UPL;
        #pragma unroll
        for (int u = 0; u < UPL; u++) {
            float a, b; b2x2(p[u], a, b);
            acc[2 * u]     = sn * a;
            acc[2 * u + 1] = sn * b;
        }
    }

    int beg = row_ptr[i], end = row_ptr[i + 1];
    for (int base = beg; base < end; base += 64) {
        int t = base + lane;
        uint2 mt;
        if (t < end) mt = meta[t]; else { mt.x = 0u; mt.y = 0u; }
        int m = end - base; if (m > 64) m = 64;
        int pairs = (m + 1) >> 1;
        #pragma unroll 4
        for (int j = 0; j < pairs; j++) {
            int e = 2 * j + h;
            int   s = __shfl((int)mt.x, e);
            uint  wu = (uint)__shfl((int)mt.y, e);
            float w = __uint_as_float(wu);
            if (e >= m) w = 0.0f;
            const uint* p = rowbase + (size_t)s * (C / 2) + cl * UPL;
            if constexpr (UPL == 4) {
                uint4 q = *(const uint4*)p;
                float a, b;
                b2x2(q.x, a, b); acc[0] += w * a; acc[1] += w * b;
                b2x2(q.y, a, b); acc[2] += w * a; acc[3] += w * b;
                b2x2(q.z, a, b); acc[4] += w * a; acc[5] += w * b;
                b2x2(q.w, a, b); acc[6] += w * a; acc[7] += w * b;
            } else {
                uint2 q = *(const uint2*)p;
                float a, b;
                b2x2(q.x, a, b); acc[0] += w * a; acc[1] += w * b;
                b2x2(q.y, a, b); acc[2] += w * a; acc[3] += w * b;
            }
        }
    }

    #pragma unroll
    for (int k = 0; k < 2 * UPL; k++) acc[k] += __shfl_xor(acc[k], 32);

    if (h == 0) {
        uint* po = (uint*)out + (size_t)i * (C / 2) + cl * UPL;
        if constexpr (UPL == 4) {
            uint4 o;
            o.x = pack2(acc[0], acc[1]);
            o.y = pack2(acc[2], acc[3]);
            o.z = pack2(acc[4], acc[5]);
            o.w = pack2(acc[6], acc[7]);
            *(uint4*)po = o;
        } else {
            uint2 o;
            o.x = pack2(acc[0], acc[1]);
            o.y = pack2(acc[2], acc[3]);
            *(uint2*)po = o;
        }
    }
}

// ---------------------------------------------------------------------------
// MFMA GEMM: C[M x 256] = relu(A[M x K](bf16) @ Wt([256][K] bf16) + bias)
// block 256 = 4 waves, BM=128 (32 rows/wave), BN=128, no LDS
// ---------------------------------------------------------------------------
template<int K>
__global__ __launch_bounds__(256) void gemm_kernel(const ushort* __restrict__ A,
                                                   const ushort* __restrict__ Bt,
                                                   const float* __restrict__ bias,
                                                   ushort* __restrict__ C, int M) {
    int wave = threadIdx.x >> 6;
    int lane = threadIdx.x & 63;
    int quad = lane >> 4;
    int r = lane & 15;
    int bm = blockIdx.x * 128 + wave * 32;
    int bn = blockIdx.y * 128;

    int rowA0 = bm + r;       if (rowA0 >= M) rowA0 = M - 1;
    int rowA1 = bm + 16 + r;  if (rowA1 >= M) rowA1 = M - 1;
    const ushort* pA0 = A + (size_t)rowA0 * K + quad * 8;
    const ushort* pA1 = A + (size_t)rowA1 * K + quad * 8;
    const ushort* pB0 = Bt + (size_t)(bn + r) * K + quad * 8;

    f32x4_t acc[2][8];
    #pragma unroll
    for (int mt = 0; mt < 2; mt++)
        #pragma unroll
        for (int nt = 0; nt < 8; nt++)
            acc[mt][nt] = (f32x4_t){0.f, 0.f, 0.f, 0.f};

    #pragma unroll 2
    for (int kt = 0; kt < K; kt += 32) {
        bf16x8_t a0 = *(const bf16x8_t*)(pA0 + kt);
        bf16x8_t a1 = *(const bf16x8_t*)(pA1 + kt);
        #pragma unroll
        for (int nt = 0; nt < 8; nt++) {
            bf16x8_t b = *(const bf16x8_t*)(pB0 + (size_t)nt * 16 * K + kt);
            acc[0][nt] = __builtin_amdgcn_mfma_f32_16x16x32_bf16(a0, b, acc[0][nt], 0, 0, 0);
            acc[1][nt] = __builtin_amdgcn_mfma_f32_16x16x32_bf16(a1, b, acc[1][nt], 0, 0, 0);
        }
    }

    #pragma unroll
    for (int mt = 0; mt < 2; mt++) {
        #pragma unroll
        for (int i = 0; i < 4; i++) {
            int grow = bm + mt * 16 + quad * 4 + i;
            if (grow < M) {
                #pragma unroll
                for (int nt = 0; nt < 8; nt++) {
                    int gcol = bn + nt * 16 + r;
                    float v = acc[mt][nt][i] + bias[gcol];
                    v = fmaxf(v, 0.0f);
                    C[(size_t)grow * 256 + gcol] = f2b(v);
                }
            }
        }
    }
}

// ---------------------------------------------------------------------------
// Pool + head
// ---------------------------------------------------------------------------
__global__ __launch_bounds__(256) void pool_kernel(const ushort* __restrict__ H,
                                                   const int* __restrict__ bp,
                                                   float* __restrict__ pooled) {
    int g = blockIdx.x, part = blockIdx.y;
    int beg = bp[g], end = bp[g + 1];
    int cnt = end - beg;
    int per = (cnt + 7) >> 3;
    int rb = beg + part * per;
    int re = rb + per; if (re > end) re = end;
    if (rb >= re) return;
    int c = threadIdx.x;
    float acc = 0.0f;
    for (int i = rb; i < re; i++) acc += b2f(H[(size_t)i * 256 + c]);
    atomicAdd(&pooled[(size_t)g * 256 + c], acc);
}

__global__ __launch_bounds__(64) void head_kernel(const float* __restrict__ pooled,
                                                  const int* __restrict__ bp,
                                                  const float* __restrict__ Wout,
                                                  const float* __restrict__ bout,
                                                  float* __restrict__ out) {
    int g = blockIdx.x;
    int lane = threadIdx.x;
    float inv = 1.0f / fmaxf((float)(bp[g + 1] - bp[g]), 1.0f);
    const float* pg = pooled + (size_t)g * HH;
    float s[TT] = {};
    for (int c = lane; c < HH; c += 64) {
        float p = pg[c] * inv;
        #pragma unroll
        for (int t = 0; t < TT; t++) s[t] += p * Wout[c * TT + t];
    }
    #pragma unroll
    for (int t = 0; t < TT; t++) {
        float v = s[t];
        for (int off = 32; off > 0; off >>= 1) v += __shfl_down(v, off);
        if (lane == 0) out[(size_t)g * TT + t] = v + bout[t];
    }
}

// ---------------------------------------------------------------------------
// Launch
// ---------------------------------------------------------------------------
extern "C" void kernel_launch(void* const* d_in, const int* in_sizes, int n_in,
                              void* d_out, int out_size, void* d_ws, size_t ws_size,
                              hipStream_t stream) {
    const float* x     = (const float*)d_in[0];
    const int*   esrc  = (const int*)d_in[1];
    const int*   edst  = ((const int*)d_in[1]) + EE;
    const int*   batch = (const int*)d_in[2];
    const float* W0 = (const float*)d_in[3];  const float* b0 = (const float*)d_in[4];
    const float* W1 = (const float*)d_in[5];  const float* b1 = (const float*)d_in[6];
    const float* W2 = (const float*)d_in[7];  const float* b2 = (const float*)d_in[8];
    const float* W3 = (const float*)d_in[9];  const float* b3 = (const float*)d_in[10];
    const float* Wout = (const float*)d_in[11]; const float* bout = (const float*)d_in[12];
    float* out = (float*)d_out;

    char* p = (char*)d_ws;
    size_t off = 0;
    auto alloc = [&](size_t bytes) {
        void* r = p + off;
        off += (bytes + 255) & ~(size_t)255;
        return r;
    };
    int*    cnt      = (int*)alloc((size_t)NN * 4);
    int*    row_ptr  = (int*)alloc((size_t)(NN + 1) * 4);
    int*    cursor   = (int*)alloc((size_t)NN * 4);
    float*  dinv     = (float*)alloc((size_t)NN * 4);
    float*  selfnorm = (float*)alloc((size_t)NN * 4);
    int*    bsum     = (int*)alloc(256 * 4);
    int*    boff     = (int*)alloc(256 * 4);
    int*    bp       = (int*)alloc((size_t)(GG + 1) * 4);
    uint2*  meta     = (uint2*)alloc((size_t)EE * 8);
    ushort* xb       = (ushort*)alloc((size_t)NN * FF * 2);
    ushort* aggX     = (ushort*)alloc((size_t)NN * FF * 2);
    ushort* hA       = (ushort*)alloc((size_t)NN * HH * 2);
    ushort* hB       = (ushort*)alloc((size_t)NN * HH * 2);
    ushort* Wt0      = (ushort*)alloc((size_t)FF * HH * 2);
    ushort* Wt1      = (ushort*)alloc((size_t)HH * HH * 2);
    ushort* Wt2      = (ushort*)alloc((size_t)HH * HH * 2);
    ushort* Wt3      = (ushort*)alloc((size_t)HH * HH * 2);
    float*  pooled   = (float*)alloc((size_t)GG * HH * 4);
    (void)ws_size;

    const int NB = (NN + 255) / 256;

    hipMemsetAsync(cnt, 0, (size_t)NN * 4, stream);
    hipMemsetAsync(pooled, 0, (size_t)GG * HH * 4, stream);
    count_kernel<<<(EE + 255) / 256, 256, 0, stream>>>(edst, cnt, EE);
    blocksum_kernel<<<NB, 256, 0, stream>>>(cnt, bsum, NN);
    scanb_kernel<<<1, 256, 0, stream>>>(bsum, boff, NB);
    rowptr_kernel<<<NB, 256, 0, stream>>>(cnt, boff, row_ptr, cursor, dinv, selfnorm, NN);
    scatter_kernel<<<(EE + 255) / 256, 256, 0, stream>>>(esrc, edst, row_ptr, cursor,
                                                         meta, dinv, EE);
    bp_kernel<<<(GG + 64) / 64, 64, 0, stream>>>(batch, bp, NN, GG);

    cvtx_kernel<<<(NN * FF / 4 + 255) / 256, 256, 0, stream>>>(x, xb, NN * FF / 4);
    wt_all_kernel<<<FF + 3 * HH, 256, 0, stream>>>(W0, W1, W2, W3, Wt0, Wt1, Wt2, Wt3);

    dim3 ggrid((NN + 127) / 128, 2);
    int aggblocks = (NN + 3) / 4;

    agg_kernel<FF><<<aggblocks, 256, 0, stream>>>(xb, row_ptr, meta, selfnorm, aggX);
    gemm_kernel<FF><<<ggrid, 256, 0, stream>>>(aggX, Wt0, b0, hA, NN);
    agg_kernel<HH><<<aggblocks, 256, 0, stream>>>(hA, row_ptr, meta, selfnorm, hB);
    gemm_kernel<HH><<<ggrid, 256, 0, stream>>>(hB, Wt1, b1, hA, NN);
    agg_kernel<HH><<<aggblocks, 256, 0, stream>>>(hA, row_ptr, meta, selfnorm, hB);
    gemm_kernel<HH><<<ggrid, 256, 0, stream>>>(hB, Wt2, b2, hA, NN);
    agg_kernel<HH><<<aggblocks, 256, 0, stream>>>(hA, row_ptr, meta, selfnorm, hB);
    gemm_kernel<HH><<<ggrid, 256, 0, stream>>>(hB, Wt3, b3, hA, NN);

    dim3 pgrid(GG, 8);
    pool_kernel<<<pgrid, 256, 0, stream>>>(hA, bp, pooled);
    head_kernel<<<GG, 64, 0, stream>>>(pooled, bp, Wout, bout, out);
}